// Round 6
// baseline (152916.064 us; speedup 1.0000x reference)
//
#include <hip/hip_runtime.h>
#include <math.h>

#define Bx 64
#define Tx 800
#define Ux 80
#define INx 3
#define Hx 400
#define Vx 57
#define Kx 10
#define TT 50      // steps per xg chunk (layers 1/2)
#define NC 16      // chunks per layer

// Activation layouts (b fastest):
//  out0/out12 : t*25600 + h*64 + b
//  win        : t*3648  + v*64 + b
//  abk        : t*1920  + j*64 + b
//  xT         : t*192   + d*64 + b
//  ohT        : (u*57+v)*64 + b
//  xg chunk   : tt*76800 + row*64 + b     (row 0..1199, incl b_ih)
//
// k_rec: 64 WGs = 16 u-slices (25 units) x 4 chain-groups (16 chains).
// Whh slice (75 rows x 400 k = 120 KB) lives in DYNAMIC LDS -> immune to the
// per-step agent-scope acquire (L2 invalidate) that killed R4 (weight refetch).
// Per step: stage h (25.6 KB from global) -> dot (pk_fma, partials in LDS) ->
// activation + h_new store -> 16-WG barrier per chain-group (tid0 only).

typedef float v2f __attribute__((ext_vector_type(2)));
typedef float v4f __attribute__((ext_vector_type(4)));

__device__ __forceinline__ float sigf(float x) { return 1.f / (1.f + expf(-x)); }

// acc.xy += w.x * h.xy   (broadcast LOW half of S0)  [verified R2..R5]
__device__ __forceinline__ void pk_lo(v2f& acc, v2f w, v2f h) {
    asm("v_pk_fma_f32 %0, %1, %2, %0 op_sel:[0,0,0] op_sel_hi:[0,1,1]"
        : "+v"(acc) : "v"(w), "v"(h));
}
// acc.xy += w.y * h.xy   (broadcast HIGH half of S0)
__device__ __forceinline__ void pk_hi(v2f& acc, v2f w, v2f h) {
    asm("v_pk_fma_f32 %0, %1, %2, %0 op_sel:[1,0,0] op_sel_hi:[1,1,1]"
        : "+v"(acc) : "v"(w), "v"(h));
}

__global__ void k_zero(int* __restrict__ cnt) {
    int i = blockIdx.x * blockDim.x + threadIdx.x;
    if (i < 1536) cnt[i] = 0;
}

__global__ void k_transpose_x(const float* __restrict__ x, float* __restrict__ xT) {
    int idx = blockIdx.x * blockDim.x + threadIdx.x;
    if (idx >= Tx * INx * Bx) return;
    int b = idx & 63;
    int d = (idx >> 6) % INx;
    int t = idx / (64 * INx);
    xT[idx] = x[((size_t)b * Tx + t) * INx + d];
}

__global__ void k_transpose_oh(const float* __restrict__ oh, float* __restrict__ ohT) {
    int idx = blockIdx.x * blockDim.x + threadIdx.x;
    if (idx >= Ux * Vx * Bx) return;
    int b = idx & 63;
    int uv = idx >> 6;
    int v = uv % Vx;
    int u = uv / Vx;
    ohT[idx] = oh[((size_t)b * Ux + u) * Vx + v];
}

// Persistent-ish GRU recurrence over [t0, t0+nt).
// L0=1: x-side fused from xT (3 cols) + Wih0; L0=0: x-side from xg chunk.
template <int L0>
__global__ __launch_bounds__(512, 1) void k_rec(
    const float* __restrict__ Whh, const float* __restrict__ xg,
    const float* __restrict__ xT, const float* __restrict__ hinit,
    const float* __restrict__ Wih0, const float* __restrict__ bih,
    const float* __restrict__ bhh, float* __restrict__ outL,
    int* __restrict__ cnt, int t0, int nt) {
    extern __shared__ float wlds[];            // [3][25][400] = 120,000 B
    __shared__ float hls[8 * 404 * 2];         // v2f [cp][404(pad)] : h, 2 chains per cp
    __shared__ float pls[1200 * 2];            // v2f partials [(u*2+ks)*8+cp][3g]
    __shared__ float bias_h[75];               // [g*25+u]
    __shared__ float bias_x[75];               // L0 only
    __shared__ float wih0s[225];               // L0 only [ (g*25+u)*3 + d ]

    const int tid = threadIdx.x;
    const int us = blockIdx.x & 15;
    const int cg = blockIdx.x >> 4;
    const int cb = cg * 16;
    const int U0 = us * 25;
    int* cnt_cg = cnt + cg * 32;

    // ---- one-time: weights slice -> LDS (rows g*400+U0+u, all k)
    for (int idx = tid; idx < 30000; idx += 512) {
        int g = idx / 10000;
        int rem = idx - g * 10000;
        int u = rem / 400;
        int k = rem - u * 400;
        wlds[(g * 25 + u) * 400 + k] = Whh[(size_t)(g * 400 + U0 + u) * 400 + k];
    }
    if (tid < 75) bias_h[tid] = bhh[(tid / 25) * 400 + U0 + (tid % 25)];
    if (L0) {
        if (tid >= 128 && tid < 203) {
            int i = tid - 128;
            bias_x[i] = bih[(i / 25) * 400 + U0 + (i % 25)];
        }
        if (tid >= 256 && tid < 481) {
            int i = tid - 256;             // i = (g*25+u)*3 + d
            int gu = i / 3, d = i - gu * 3;
            int g = gu / 25, u = gu - g * 25;
            wih0s[i] = Wih0[(size_t)(g * 400 + U0 + u) * 3 + d];
        }
    }
    __syncthreads();

    v2f* hv = (v2f*)hls;
    v2f* pp = (v2f*)pls;

    for (int tt = 0; tt < nt; ++tt) {
        const int t = t0 + tt;

        // ---- stage h(t-1) -> LDS  (global, post-acquire so other WGs' slices visible)
        if (t == 0) {
            for (int idx = tid; idx < 3200; idx += 512) {
                int k = idx >> 3, cp = idx & 7;
                v2f hvv;
                hvv.x = hinit[(size_t)(cb + 2 * cp) * 400 + k];
                hvv.y = hinit[(size_t)(cb + 2 * cp + 1) * 400 + k];
                hv[cp * 404 + k] = hvv;
            }
        } else {
            const float* hsrc = outL + (size_t)(t - 1) * 25600 + cb;
            for (int idx = tid; idx < 3200; idx += 512) {
                int k = idx >> 3, cp = idx & 7;
                hv[cp * 404 + k] = *(const v2f*)(hsrc + k * 64 + 2 * cp);
            }
        }
        __syncthreads();

        // ---- dot: tid<400 = (u 25, ks 2, cq 8); 200-k segment, 2 chains
        if (tid < 400) {
            int u = tid >> 4;
            int r = tid & 15;
            int ks = r >> 3;
            int cq = r & 7;
            int k0 = ks * 200;
            v2f acc0 = {0, 0}, acc1 = {0, 0}, acc2 = {0, 0};
            const float* w0 = &wlds[(0 * 25 + u) * 400 + k0];
            const float* w1 = &wlds[(1 * 25 + u) * 400 + k0];
            const float* w2 = &wlds[(2 * 25 + u) * 400 + k0];
            const v2f* hb = &hv[cq * 404 + k0];
            #pragma unroll 4
            for (int kp = 0; kp < 100; ++kp) {
                v4f hh = *(const v4f*)(hb + 2 * kp);       // h[k0..k1] x 2 chains
                v2f wa = *(const v2f*)(w0 + 2 * kp);
                v2f wb = *(const v2f*)(w1 + 2 * kp);
                v2f wc = *(const v2f*)(w2 + 2 * kp);
                pk_lo(acc0, wa, hh.xy); pk_hi(acc0, wa, hh.zw);
                pk_lo(acc1, wb, hh.xy); pk_hi(acc1, wb, hh.zw);
                pk_lo(acc2, wc, hh.xy); pk_hi(acc2, wc, hh.zw);
            }
            int pb = ((u * 2 + ks) * 8 + cq) * 3;
            pp[pb + 0] = acc0;
            pp[pb + 1] = acc1;
            pp[pb + 2] = acc2;
        }
        __syncthreads();

        // ---- activation: tid<200 = (u 25, cp 8); 2 chains
        if (tid < 200) {
            int u = tid >> 3;
            int cp = tid & 7;
            v2f R = pp[((u * 2 + 0) * 8 + cp) * 3 + 0] + pp[((u * 2 + 1) * 8 + cp) * 3 + 0];
            v2f Z = pp[((u * 2 + 0) * 8 + cp) * 3 + 1] + pp[((u * 2 + 1) * 8 + cp) * 3 + 1];
            v2f N = pp[((u * 2 + 0) * 8 + cp) * 3 + 2] + pp[((u * 2 + 1) * 8 + cp) * 3 + 2];
            v2f XR, XZ, XN;
            if (L0) {
                v2f x0 = *(const v2f*)(xT + (size_t)t * 192 + 0 * 64 + cb + 2 * cp);
                v2f x1 = *(const v2f*)(xT + (size_t)t * 192 + 1 * 64 + cb + 2 * cp);
                v2f x2 = *(const v2f*)(xT + (size_t)t * 192 + 2 * 64 + cb + 2 * cp);
                const float* wr = &wih0s[(0 * 25 + u) * 3];
                const float* wz = &wih0s[(1 * 25 + u) * 3];
                const float* wn = &wih0s[(2 * 25 + u) * 3];
                XR = bias_x[u]      + wr[0] * x0 + wr[1] * x1 + wr[2] * x2;
                XZ = bias_x[25 + u] + wz[0] * x0 + wz[1] * x1 + wz[2] * x2;
                XN = bias_x[50 + u] + wn[0] * x0 + wn[1] * x1 + wn[2] * x2;
            } else {
                const float* xb = xg + (size_t)tt * 76800 + cb + 2 * cp;
                XR = *(const v2f*)(xb + (size_t)(U0 + u) * 64);
                XZ = *(const v2f*)(xb + (size_t)(400 + U0 + u) * 64);
                XN = *(const v2f*)(xb + (size_t)(800 + U0 + u) * 64);
            }
            float bhr = bias_h[u], bhz = bias_h[25 + u], bhn = bias_h[50 + u];
            v2f hp = hv[cp * 404 + U0 + u];
            v2f hn2;
            #pragma unroll
            for (int e = 0; e < 2; ++e) {
                float rr = sigf(XR[e] + R[e] + bhr);
                float zz = sigf(XZ[e] + Z[e] + bhz);
                float nn = tanhf(XN[e] + rr * (N[e] + bhn));
                hn2[e] = (1.f - zz) * nn + zz * hp[e];
            }
            *(v2f*)(outL + (size_t)t * 25600 + (U0 + u) * 64 + cb + 2 * cp) = hn2;
        }
        __syncthreads();

        // ---- 16-WG barrier per chain-group (skip final spin; kernel boundary syncs)
        if (tid == 0) {
            __threadfence();
            __hip_atomic_fetch_add(cnt_cg, 1, __ATOMIC_RELEASE, __HIP_MEMORY_SCOPE_AGENT);
            if (tt + 1 < nt) {
                int target = 16 * (t + 1);
                while (__hip_atomic_load(cnt_cg, __ATOMIC_ACQUIRE, __HIP_MEMORY_SCOPE_AGENT) < target)
                    __builtin_amdgcn_s_sleep(1);
            }
        }
        __syncthreads();
    }
}

// abk = exp(out0 @ W_win^T + b_win), parallel over t. grid 800 x 256.
__global__ __launch_bounds__(256) void k_abk(const float* __restrict__ out0,
    const float* __restrict__ Wwin, const float* __restrict__ bwin,
    float* __restrict__ abk) {
    int t = blockIdx.x;
    int b = threadIdx.x & 63;
    int js = threadIdx.x >> 6;
    int j0 = js * 8;
    int nj = min(8, 30 - j0);
    float acc[8];
    for (int i = 0; i < nj; i++) acc[i] = bwin[j0 + i];
    const float* o = out0 + (size_t)t * 25600;
    for (int k = 0; k < Hx; k++) {
        float hvv = o[k * 64 + b];
        for (int i = 0; i < nj; i++) acc[i] += Wwin[(j0 + i) * Hx + k] * hvv;
    }
    for (int i = 0; i < nj; i++)
        abk[(size_t)t * 1920 + (j0 + i) * 64 + b] = expf(acc[i]);
}

__global__ void k_cumsum(float* __restrict__ abk) {
    int tid = blockIdx.x * blockDim.x + threadIdx.x;
    if (tid >= Kx * Bx) return;
    int b = tid & 63;
    int k = tid >> 6;
    float run = 0.f;
    size_t base = (size_t)(20 + k) * 64 + b;
    for (int t = 0; t < Tx; t++) {
        size_t i = (size_t)t * 1920 + base;
        run += abk[i];
        abk[i] = run;
    }
}

__global__ __launch_bounds__(256) void k_window(const float* __restrict__ abk,
    const float* __restrict__ ohT, float* __restrict__ win) {
    int t = blockIdx.x;
    int b = threadIdx.x & 63;
    int sub = threadIdx.x >> 6;
    __shared__ float phi[Ux][64];

    float al[Kx], be[Kx], kc[Kx];
    const float* ab = abk + (size_t)t * 1920;
    #pragma unroll
    for (int k = 0; k < Kx; k++) {
        al[k] = ab[k * 64 + b];
        be[k] = ab[(10 + k) * 64 + b];
        kc[k] = ab[(20 + k) * 64 + b];
    }
    for (int u = sub * 20; u < sub * 20 + 20; u++) {
        float ssum = 0.f;
        float uf = (float)u;
        #pragma unroll
        for (int k = 0; k < Kx; k++) {
            float d = kc[k] - uf;
            ssum += al[k] * __expf(-be[k] * d * d);
        }
        phi[u][b] = ssum;
    }
    __syncthreads();

    int v0 = sub * 15;
    int nv = min(15, Vx - v0);
    float acc[15];
    for (int i = 0; i < nv; i++) acc[i] = 0.f;
    for (int u = 0; u < Ux; u++) {
        float pv = phi[u][b];
        const float* oh = ohT + (size_t)(u * Vx) * 64;
        for (int i = 0; i < nv; i++) acc[i] += pv * oh[(v0 + i) * 64 + b];
    }
    for (int i = 0; i < nv; i++)
        win[(size_t)t * 3648 + (v0 + i) * 64 + b] = acc[i];
}

// Input-side projection for layers 1/2, one TT-step chunk. grid (TT, 75) x 256.
__global__ __launch_bounds__(256) void k_xg(const float* __restrict__ outprev,
    const float* __restrict__ win, const float* __restrict__ xT,
    const float* __restrict__ Wih, const float* __restrict__ bih,
    float* __restrict__ xg, int t0) {
    int tt = blockIdx.x;
    int gt = blockIdx.y;
    int t = t0 + tt;
    int b = threadIdx.x & 63;
    int du = threadIdx.x >> 6;
    int g = gt * 16 + du * 4;

    float a0 = bih[g], a1 = bih[g + 1], a2 = bih[g + 2], a3 = bih[g + 3];
    const float* w0 = Wih + (size_t)g * 460;
    const float* w1 = w0 + 460;
    const float* w2 = w0 + 920;
    const float* w3 = w0 + 1380;

    const float* op = outprev + (size_t)t * 25600;
    for (int d = 0; d < 400; d += 4) {
        float4 q0 = *(const float4*)(w0 + d);
        float4 q1 = *(const float4*)(w1 + d);
        float4 q2 = *(const float4*)(w2 + d);
        float4 q3 = *(const float4*)(w3 + d);
        float i0 = op[d * 64 + b];
        float i1 = op[(d + 1) * 64 + b];
        float i2 = op[(d + 2) * 64 + b];
        float i3 = op[(d + 3) * 64 + b];
        a0 += q0.x * i0 + q0.y * i1 + q0.z * i2 + q0.w * i3;
        a1 += q1.x * i0 + q1.y * i1 + q1.z * i2 + q1.w * i3;
        a2 += q2.x * i0 + q2.y * i1 + q2.z * i2 + q2.w * i3;
        a3 += q3.x * i0 + q3.y * i1 + q3.z * i2 + q3.w * i3;
    }
    const float* wp = win + (size_t)t * 3648;
    for (int d = 0; d < Vx; d++) {
        float iv = wp[d * 64 + b];
        a0 += w0[400 + d] * iv;
        a1 += w1[400 + d] * iv;
        a2 += w2[400 + d] * iv;
        a3 += w3[400 + d] * iv;
    }
    const float* xp = xT + (size_t)t * 192;
    #pragma unroll
    for (int d = 0; d < 3; d++) {
        float iv = xp[d * 64 + b];
        a0 += w0[457 + d] * iv;
        a1 += w1[457 + d] * iv;
        a2 += w2[457 + d] * iv;
        a3 += w3[457 + d] * iv;
    }
    size_t o = (size_t)tt * 76800 + (size_t)g * 64 + b;
    xg[o] = a0;
    xg[o + 64] = a1;
    xg[o + 128] = a2;
    xg[o + 192] = a3;
}

// MDN head: out[(b*T+t)*121 + j], tanh on j in [100,120). grid 800 x 256.
__global__ __launch_bounds__(256) void k_mdn(const float* __restrict__ out2,
    const float* __restrict__ Wm, const float* __restrict__ bm,
    float* __restrict__ out) {
    int t = blockIdx.x;
    int b = threadIdx.x & 63;
    int js = threadIdx.x >> 6;
    int j0 = js * 31;
    int nj = min(31, 121 - j0);
    float acc[31];
    for (int i = 0; i < nj; i++) acc[i] = bm[j0 + i];
    const float* o = out2 + (size_t)t * 25600;
    for (int k = 0; k < Hx; k += 4) {
        float i0 = o[k * 64 + b];
        float i1 = o[(k + 1) * 64 + b];
        float i2 = o[(k + 2) * 64 + b];
        float i3 = o[(k + 3) * 64 + b];
        for (int i = 0; i < nj; i++) {
            const float* wp = Wm + (size_t)(j0 + i) * Hx + k;
            float4 qv = *(const float4*)wp;
            acc[i] += qv.x * i0 + qv.y * i1 + qv.z * i2 + qv.w * i3;
        }
    }
    size_t rb = ((size_t)b * Tx + t) * 121;
    for (int i = 0; i < nj; i++) {
        int j = j0 + i;
        float v = acc[i];
        if (j >= 100 && j < 120) v = tanhf(v);
        out[rb + j] = v;
    }
}

extern "C" void kernel_launch(void* const* d_in, const int* in_sizes, int n_in,
                              void* d_out, int out_size, void* d_ws, size_t ws_size,
                              hipStream_t stream) {
    const float* x    = (const float*)d_in[0];
    const float* oneh = (const float*)d_in[1];
    const float* h0i  = (const float*)d_in[2];
    const float* h1i  = (const float*)d_in[3];
    const float* h2i  = (const float*)d_in[4];
    const float* Wih0 = (const float*)d_in[5];
    const float* Whh0 = (const float*)d_in[6];
    const float* bih0 = (const float*)d_in[7];
    const float* bhh0 = (const float*)d_in[8];
    const float* Wih1 = (const float*)d_in[9];
    const float* Whh1 = (const float*)d_in[10];
    const float* bih1 = (const float*)d_in[11];
    const float* bhh1 = (const float*)d_in[12];
    const float* Wwin = (const float*)d_in[13];
    const float* bwin = (const float*)d_in[14];
    const float* Wmdn = (const float*)d_in[15];
    const float* bmdn = (const float*)d_in[16];

    float* ws    = (float*)d_ws;
    float* out0  = ws;                    // 20,480,000
    float* out12 = ws + 20480000;         // 20,480,000
    float* winb  = ws + 40960000;         //  2,918,400
    float* abk   = ws + 43878400;         //  1,536,000
    float* xg    = ws + 45414400;         //  3,840,000 (TT=50 chunk)
    float* xT    = ws + 49254400;         //    153,600
    float* ohT   = ws + 49408000;         //    291,840
    int*   cnt   = (int*)(ws + 49699840); //      1,536 ints
    // total ~49.7M floats ≈ 199 MB

    const int DYN = 120000;  // dynamic LDS bytes for wlds
    (void)hipFuncSetAttribute((const void*)&k_rec<1>,
        hipFuncAttributeMaxDynamicSharedMemorySize, DYN);
    (void)hipFuncSetAttribute((const void*)&k_rec<0>,
        hipFuncAttributeMaxDynamicSharedMemorySize, DYN);

    hipLaunchKernelGGL(k_zero, dim3(6), dim3(256), 0, stream, cnt);
    hipLaunchKernelGGL(k_transpose_x, dim3((Tx * INx * Bx + 255) / 256), dim3(256), 0, stream, x, xT);
    hipLaunchKernelGGL(k_transpose_oh, dim3((Ux * Vx * Bx + 255) / 256), dim3(256), 0, stream, oneh, ohT);

    // Layer 0: one launch, 800 steps
    hipLaunchKernelGGL((k_rec<1>), dim3(64), dim3(512), DYN, stream,
                       Whh0, (const float*)nullptr, xT, h0i, Wih0, bih0, bhh0,
                       out0, cnt + 0, 0, Tx);

    hipLaunchKernelGGL(k_abk, dim3(Tx), dim3(256), 0, stream, out0, Wwin, bwin, abk);
    hipLaunchKernelGGL(k_cumsum, dim3(10), dim3(64), 0, stream, abk);
    hipLaunchKernelGGL(k_window, dim3(Tx), dim3(256), 0, stream, abk, ohT, winb);

    // Layer 1: chunked xg + recurrence
    for (int c = 0; c < NC; c++) {
        hipLaunchKernelGGL(k_xg, dim3(TT, 75), dim3(256), 0, stream,
                           out0, winb, xT, Wih1, bih1, xg, c * TT);
        hipLaunchKernelGGL((k_rec<0>), dim3(64), dim3(512), DYN, stream,
                           Whh1, xg, xT, h1i, (const float*)nullptr, bih1, bhh1,
                           out12, cnt + 256, c * TT, TT);
    }
    // Layer 2 (same weights), output reuses out0
    for (int c = 0; c < NC; c++) {
        hipLaunchKernelGGL(k_xg, dim3(TT, 75), dim3(256), 0, stream,
                           out12, winb, xT, Wih1, bih1, xg, c * TT);
        hipLaunchKernelGGL((k_rec<0>), dim3(64), dim3(512), DYN, stream,
                           Whh1, xg, xT, h2i, (const float*)nullptr, bih1, bhh1,
                           out0, cnt + 512, c * TT, TT);
    }
    hipLaunchKernelGGL(k_mdn, dim3(Tx), dim3(256), 0, stream, out0, Wmdn, bmdn, (float*)d_out);
}

// Round 7
// 61977.826 us; speedup vs baseline: 2.4673x; 2.4673x over previous
//
#include <hip/hip_runtime.h>
#include <math.h>

#define Bx 64
#define Tx 800
#define Ux 80
#define INx 3
#define Hx 400
#define Vx 57
#define Kx 10
#define TT 50      // steps per xg chunk (layers 1/2)
#define NC 16      // chunks per layer

// Activation layouts (b fastest):
//  out0/out12 : t*25600 + h*64 + b
//  win        : t*3648  + v*64 + b
//  abk        : t*1920  + j*64 + b
//  xT         : t*192   + d*64 + b
//  ohT        : (u*57+v)*64 + b
//  xg chunk   : tt*76800 + row*64 + b     (row 0..1199, incl b_ih)
//
// k_rec: 128 WGs = 16 row-slices (75 gate rows; Whh slice 121 KB in dynamic
// LDS) x 8 chain-groups (8 chains; cg = blockIdx&7 -> same XCD under %8
// round-robin heuristic). Thread = (row, chainpair): full-k dot, NO partial
// reduction. Cross-WG step barrier = per-WG FLAG (64B apart): release-fence
// (wbL2) + relaxed flag store; 16 lanes poll 16 flags with RELAXED loads
// (no per-poll invalidate -- R6's fatal mistake), then ONE acquire fence.

typedef float v2f __attribute__((ext_vector_type(2)));
typedef float v4f __attribute__((ext_vector_type(4)));

__device__ __forceinline__ float sigf(float x) { return 1.f / (1.f + expf(-x)); }

// acc.xy += w.x * h.xy   (broadcast LOW half of S0)  [verified R2..R6]
__device__ __forceinline__ void pk_lo(v2f& acc, v2f w, v2f h) {
    asm("v_pk_fma_f32 %0, %1, %2, %0 op_sel:[0,0,0] op_sel_hi:[0,1,1]"
        : "+v"(acc) : "v"(w), "v"(h));
}
// acc.xy += w.y * h.xy   (broadcast HIGH half of S0)
__device__ __forceinline__ void pk_hi(v2f& acc, v2f w, v2f h) {
    asm("v_pk_fma_f32 %0, %1, %2, %0 op_sel:[1,0,0] op_sel_hi:[1,1,1]"
        : "+v"(acc) : "v"(w), "v"(h));
}

__global__ void k_zero(int* __restrict__ cnt) {
    int i = blockIdx.x * blockDim.x + threadIdx.x;
    if (i < 6144) cnt[i] = 0;
}

__global__ void k_transpose_x(const float* __restrict__ x, float* __restrict__ xT) {
    int idx = blockIdx.x * blockDim.x + threadIdx.x;
    if (idx >= Tx * INx * Bx) return;
    int b = idx & 63;
    int d = (idx >> 6) % INx;
    int t = idx / (64 * INx);
    xT[idx] = x[((size_t)b * Tx + t) * INx + d];
}

__global__ void k_transpose_oh(const float* __restrict__ oh, float* __restrict__ ohT) {
    int idx = blockIdx.x * blockDim.x + threadIdx.x;
    if (idx >= Ux * Vx * Bx) return;
    int b = idx & 63;
    int uv = idx >> 6;
    int v = uv % Vx;
    int u = uv / Vx;
    ohT[idx] = oh[((size_t)b * Ux + u) * Vx + v];
}

// GRU recurrence over [t0, t0+nt). L0=1: x-side fused (3 cols); else from xg.
template <int L0>
__global__ __launch_bounds__(640, 1) void k_rec(
    const float* __restrict__ Whh, const float* __restrict__ xg,
    const float* __restrict__ xT, const float* __restrict__ hinit,
    const float* __restrict__ Wih0, const float* __restrict__ bih,
    const float* __restrict__ bhh, float* __restrict__ outL,
    int* __restrict__ flg, int t0, int nt) {
    extern __shared__ float wlds[];        // 75 rows x 404 (pad) = 121,200 B
    __shared__ __align__(16) float hls[4 * 804];   // [cp][201 v4f] = 12,864 B
    __shared__ float gates[75 * 4 * 2];            // [row][cp] v2f
    __shared__ float bias_h[75];
    __shared__ float bias_x[75];
    __shared__ float wih0s[225];

    const int tid = threadIdx.x;
    const int us = blockIdx.x >> 3;        // 16 row-slices
    const int cg = blockIdx.x & 7;         // 8 chain-groups (same-XCD heuristic)
    const int cb = cg * 8;
    const int U0 = us * 25;
    int* flgp = flg + cg * 256;            // 16 slots x 16 ints (64B apart)

    // ---- one-time: weight slice -> LDS (v4f, coalesced)
    for (int j = tid; j < 7500; j += 640) {
        int r = j / 100, q = j - r * 100;
        int row = (r / 25) * 400 + U0 + (r % 25);
        *(v4f*)&wlds[r * 404 + q * 4] = *(const v4f*)(Whh + (size_t)row * 400 + q * 4);
    }
    if (tid < 75) bias_h[tid] = bhh[(tid / 25) * 400 + U0 + (tid % 25)];
    if (L0) {
        if (tid >= 128 && tid < 203) {
            int i = tid - 128;
            bias_x[i] = bih[(i / 25) * 400 + U0 + (i % 25)];
        }
        if (tid >= 256 && tid < 481) {
            int i = tid - 256;             // (g*25+u)*3 + d
            int gu = i / 3, d = i - gu * 3;
            int g = gu / 25, u = gu - g * 25;
            wih0s[i] = Wih0[(size_t)(g * 400 + U0 + u) * 3 + d];
        }
    }
    __syncthreads();

    for (int tt = 0; tt < nt; ++tt) {
        const int t = t0 + tt;

        // ---- stage h(t-1) -> LDS  layout: float cp*804 + (k>>1)*4 + (k&1)*2
        if (t == 0) {
            for (int idx = tid; idx < 1600; idx += 640) {
                int k = idx >> 2, cp = idx & 3;
                v2f hv;
                hv.x = hinit[(size_t)(cb + 2 * cp) * 400 + k];
                hv.y = hinit[(size_t)(cb + 2 * cp + 1) * 400 + k];
                *(v2f*)&hls[cp * 804 + (k >> 1) * 4 + (k & 1) * 2] = hv;
            }
        } else {
            const float* hsrc = outL + (size_t)(t - 1) * 25600 + cb;
            for (int idx = tid; idx < 1600; idx += 640) {
                int k = idx >> 2, cp = idx & 3;
                *(v2f*)&hls[cp * 804 + (k >> 1) * 4 + (k & 1) * 2] =
                    *(const v2f*)(hsrc + k * 64 + 2 * cp);
            }
        }
        __syncthreads();

        // ---- dot: tid<300 = (r 75, cp 4); full 400-k row, 2 chains
        if (tid < 300) {
            int r = tid >> 2, cp = tid & 3;
            const v4f* wr4 = (const v4f*)&wlds[r * 404];
            const v4f* hp4 = (const v4f*)&hls[cp * 804];
            v2f accA = {0.f, 0.f}, accB = {0.f, 0.f};
            #pragma unroll 2
            for (int j = 0; j < 100; ++j) {
                v4f w4 = wr4[j];            // k = 4j..4j+3
                v4f h0 = hp4[2 * j];        // k=4j,4j+1  x 2 chains
                v4f h1 = hp4[2 * j + 1];    // k=4j+2,4j+3 x 2 chains
                pk_lo(accA, w4.xy, h0.xy); pk_hi(accA, w4.xy, h0.zw);
                pk_lo(accB, w4.zw, h1.xy); pk_hi(accB, w4.zw, h1.zw);
            }
            v2f acc = accA + accB;
            *(v2f*)&gates[(r * 4 + cp) * 2] = acc;
        }
        __syncthreads();

        // ---- activation: tid<100 = (u 25, cp 4); 2 chains
        if (tid < 100) {
            int u = tid >> 2, cp = tid & 3;
            v2f R = *(const v2f*)&gates[(u * 4 + cp) * 2];
            v2f Z = *(const v2f*)&gates[((25 + u) * 4 + cp) * 2];
            v2f N = *(const v2f*)&gates[((50 + u) * 4 + cp) * 2];
            v2f XR, XZ, XN;
            if (L0) {
                v2f x0 = *(const v2f*)(xT + (size_t)t * 192 + 0 * 64 + cb + 2 * cp);
                v2f x1 = *(const v2f*)(xT + (size_t)t * 192 + 1 * 64 + cb + 2 * cp);
                v2f x2 = *(const v2f*)(xT + (size_t)t * 192 + 2 * 64 + cb + 2 * cp);
                const float* wr = &wih0s[(0 * 25 + u) * 3];
                const float* wz = &wih0s[(1 * 25 + u) * 3];
                const float* wn = &wih0s[(2 * 25 + u) * 3];
                XR = bias_x[u]      + wr[0] * x0 + wr[1] * x1 + wr[2] * x2;
                XZ = bias_x[25 + u] + wz[0] * x0 + wz[1] * x1 + wz[2] * x2;
                XN = bias_x[50 + u] + wn[0] * x0 + wn[1] * x1 + wn[2] * x2;
            } else {
                const float* xb = xg + (size_t)tt * 76800 + cb + 2 * cp;
                XR = *(const v2f*)(xb + (size_t)(U0 + u) * 64);
                XZ = *(const v2f*)(xb + (size_t)(400 + U0 + u) * 64);
                XN = *(const v2f*)(xb + (size_t)(800 + U0 + u) * 64);
            }
            float bhr = bias_h[u], bhz = bias_h[25 + u], bhn = bias_h[50 + u];
            int kk = U0 + u;
            v2f hp = *(const v2f*)&hls[cp * 804 + (kk >> 1) * 4 + (kk & 1) * 2];
            v2f hn2;
            #pragma unroll
            for (int e = 0; e < 2; ++e) {
                float rr = sigf(XR[e] + R[e] + bhr);
                float zz = sigf(XZ[e] + Z[e] + bhz);
                float nn = tanhf(XN[e] + rr * (N[e] + bhn));
                hn2[e] = (1.f - zz) * nn + zz * hp[e];
            }
            *(v2f*)(outL + (size_t)t * 25600 + (U0 + u) * 64 + cb + 2 * cp) = hn2;
        }
        __syncthreads();   // all h' stores issued (vmcnt drained per-wave)

        // ---- flag barrier (wave 0 only): release+store own flag; relaxed-poll
        //      all 16 flags; single acquire fence. No atomic RMW anywhere.
        if (tid < 64) {
            if (tid == 0) {
                __builtin_amdgcn_fence(__ATOMIC_RELEASE, "agent");   // wbL2
                __hip_atomic_store(&flgp[us * 16], t + 1,
                                   __ATOMIC_RELAXED, __HIP_MEMORY_SCOPE_AGENT);
            }
            if (tt + 1 < nt) {
                if (tid < 16) {
                    while (__hip_atomic_load(&flgp[tid * 16],
                               __ATOMIC_RELAXED, __HIP_MEMORY_SCOPE_AGENT) < t + 1)
                        __builtin_amdgcn_s_sleep(2);
                }
                __builtin_amdgcn_fence(__ATOMIC_ACQUIRE, "agent");   // inv L1/L2
            }
        }
        __syncthreads();
    }
}

// abk = exp(out0 @ W_win^T + b_win), parallel over t. grid 800 x 256.
__global__ __launch_bounds__(256) void k_abk(const float* __restrict__ out0,
    const float* __restrict__ Wwin, const float* __restrict__ bwin,
    float* __restrict__ abk) {
    int t = blockIdx.x;
    int b = threadIdx.x & 63;
    int js = threadIdx.x >> 6;
    int j0 = js * 8;
    int nj = min(8, 30 - j0);
    float acc[8];
    for (int i = 0; i < nj; i++) acc[i] = bwin[j0 + i];
    const float* o = out0 + (size_t)t * 25600;
    for (int k = 0; k < Hx; k++) {
        float hvv = o[k * 64 + b];
        for (int i = 0; i < nj; i++) acc[i] += Wwin[(j0 + i) * Hx + k] * hvv;
    }
    for (int i = 0; i < nj; i++)
        abk[(size_t)t * 1920 + (j0 + i) * 64 + b] = expf(acc[i]);
}

__global__ void k_cumsum(float* __restrict__ abk) {
    int tid = blockIdx.x * blockDim.x + threadIdx.x;
    if (tid >= Kx * Bx) return;
    int b = tid & 63;
    int k = tid >> 6;
    float run = 0.f;
    size_t base = (size_t)(20 + k) * 64 + b;
    for (int t = 0; t < Tx; t++) {
        size_t i = (size_t)t * 1920 + base;
        run += abk[i];
        abk[i] = run;
    }
}

__global__ __launch_bounds__(256) void k_window(const float* __restrict__ abk,
    const float* __restrict__ ohT, float* __restrict__ win) {
    int t = blockIdx.x;
    int b = threadIdx.x & 63;
    int sub = threadIdx.x >> 6;
    __shared__ float phi[Ux][64];

    float al[Kx], be[Kx], kc[Kx];
    const float* ab = abk + (size_t)t * 1920;
    #pragma unroll
    for (int k = 0; k < Kx; k++) {
        al[k] = ab[k * 64 + b];
        be[k] = ab[(10 + k) * 64 + b];
        kc[k] = ab[(20 + k) * 64 + b];
    }
    for (int u = sub * 20; u < sub * 20 + 20; u++) {
        float ssum = 0.f;
        float uf = (float)u;
        #pragma unroll
        for (int k = 0; k < Kx; k++) {
            float d = kc[k] - uf;
            ssum += al[k] * __expf(-be[k] * d * d);
        }
        phi[u][b] = ssum;
    }
    __syncthreads();

    int v0 = sub * 15;
    int nv = min(15, Vx - v0);
    float acc[15];
    for (int i = 0; i < nv; i++) acc[i] = 0.f;
    for (int u = 0; u < Ux; u++) {
        float pv = phi[u][b];
        const float* oh = ohT + (size_t)(u * Vx) * 64;
        for (int i = 0; i < nv; i++) acc[i] += pv * oh[(v0 + i) * 64 + b];
    }
    for (int i = 0; i < nv; i++)
        win[(size_t)t * 3648 + (v0 + i) * 64 + b] = acc[i];
}

// Input-side projection for layers 1/2, one TT-step chunk. grid (TT, 75) x 256.
__global__ __launch_bounds__(256) void k_xg(const float* __restrict__ outprev,
    const float* __restrict__ win, const float* __restrict__ xT,
    const float* __restrict__ Wih, const float* __restrict__ bih,
    float* __restrict__ xg, int t0) {
    int tt = blockIdx.x;
    int gt = blockIdx.y;
    int t = t0 + tt;
    int b = threadIdx.x & 63;
    int du = threadIdx.x >> 6;
    int g = gt * 16 + du * 4;

    float a0 = bih[g], a1 = bih[g + 1], a2 = bih[g + 2], a3 = bih[g + 3];
    const float* w0 = Wih + (size_t)g * 460;
    const float* w1 = w0 + 460;
    const float* w2 = w0 + 920;
    const float* w3 = w0 + 1380;

    const float* op = outprev + (size_t)t * 25600;
    for (int d = 0; d < 400; d += 4) {
        float4 q0 = *(const float4*)(w0 + d);
        float4 q1 = *(const float4*)(w1 + d);
        float4 q2 = *(const float4*)(w2 + d);
        float4 q3 = *(const float4*)(w3 + d);
        float i0 = op[d * 64 + b];
        float i1 = op[(d + 1) * 64 + b];
        float i2 = op[(d + 2) * 64 + b];
        float i3 = op[(d + 3) * 64 + b];
        a0 += q0.x * i0 + q0.y * i1 + q0.z * i2 + q0.w * i3;
        a1 += q1.x * i0 + q1.y * i1 + q1.z * i2 + q1.w * i3;
        a2 += q2.x * i0 + q2.y * i1 + q2.z * i2 + q2.w * i3;
        a3 += q3.x * i0 + q3.y * i1 + q3.z * i2 + q3.w * i3;
    }
    const float* wp = win + (size_t)t * 3648;
    for (int d = 0; d < Vx; d++) {
        float iv = wp[d * 64 + b];
        a0 += w0[400 + d] * iv;
        a1 += w1[400 + d] * iv;
        a2 += w2[400 + d] * iv;
        a3 += w3[400 + d] * iv;
    }
    const float* xp = xT + (size_t)t * 192;
    #pragma unroll
    for (int d = 0; d < 3; d++) {
        float iv = xp[d * 64 + b];
        a0 += w0[457 + d] * iv;
        a1 += w1[457 + d] * iv;
        a2 += w2[457 + d] * iv;
        a3 += w3[457 + d] * iv;
    }
    size_t o = (size_t)tt * 76800 + (size_t)g * 64 + b;
    xg[o] = a0;
    xg[o + 64] = a1;
    xg[o + 128] = a2;
    xg[o + 192] = a3;
}

// MDN head: out[(b*T+t)*121 + j], tanh on j in [100,120). grid 800 x 256.
__global__ __launch_bounds__(256) void k_mdn(const float* __restrict__ out2,
    const float* __restrict__ Wm, const float* __restrict__ bm,
    float* __restrict__ out) {
    int t = blockIdx.x;
    int b = threadIdx.x & 63;
    int js = threadIdx.x >> 6;
    int j0 = js * 31;
    int nj = min(31, 121 - j0);
    float acc[31];
    for (int i = 0; i < nj; i++) acc[i] = bm[j0 + i];
    const float* o = out2 + (size_t)t * 25600;
    for (int k = 0; k < Hx; k += 4) {
        float i0 = o[k * 64 + b];
        float i1 = o[(k + 1) * 64 + b];
        float i2 = o[(k + 2) * 64 + b];
        float i3 = o[(k + 3) * 64 + b];
        for (int i = 0; i < nj; i++) {
            const float* wp = Wm + (size_t)(j0 + i) * Hx + k;
            float4 qv = *(const float4*)wp;
            acc[i] += qv.x * i0 + qv.y * i1 + qv.z * i2 + qv.w * i3;
        }
    }
    size_t rb = ((size_t)b * Tx + t) * 121;
    for (int i = 0; i < nj; i++) {
        int j = j0 + i;
        float v = acc[i];
        if (j >= 100 && j < 120) v = tanhf(v);
        out[rb + j] = v;
    }
}

extern "C" void kernel_launch(void* const* d_in, const int* in_sizes, int n_in,
                              void* d_out, int out_size, void* d_ws, size_t ws_size,
                              hipStream_t stream) {
    const float* x    = (const float*)d_in[0];
    const float* oneh = (const float*)d_in[1];
    const float* h0i  = (const float*)d_in[2];
    const float* h1i  = (const float*)d_in[3];
    const float* h2i  = (const float*)d_in[4];
    const float* Wih0 = (const float*)d_in[5];
    const float* Whh0 = (const float*)d_in[6];
    const float* bih0 = (const float*)d_in[7];
    const float* bhh0 = (const float*)d_in[8];
    const float* Wih1 = (const float*)d_in[9];
    const float* Whh1 = (const float*)d_in[10];
    const float* bih1 = (const float*)d_in[11];
    const float* bhh1 = (const float*)d_in[12];
    const float* Wwin = (const float*)d_in[13];
    const float* bwin = (const float*)d_in[14];
    const float* Wmdn = (const float*)d_in[15];
    const float* bmdn = (const float*)d_in[16];

    float* ws    = (float*)d_ws;
    float* out0  = ws;                    // 20,480,000
    float* out12 = ws + 20480000;         // 20,480,000
    float* winb  = ws + 40960000;         //  2,918,400
    float* abk   = ws + 43878400;         //  1,536,000
    float* xg    = ws + 45414400;         //  3,840,000 (TT=50 chunk)
    float* xT    = ws + 49254400;         //    153,600
    float* ohT   = ws + 49408000;         //    291,840
    int*   cnt   = (int*)(ws + 49699840); //      6,144 ints (3 flag regions)
    // total < 200 MB (ws >= 208 MB proven in R1)

    const int DYN = 121216;  // dynamic LDS bytes for wlds (75 x 404 floats)
    (void)hipFuncSetAttribute((const void*)&k_rec<1>,
        hipFuncAttributeMaxDynamicSharedMemorySize, DYN);
    (void)hipFuncSetAttribute((const void*)&k_rec<0>,
        hipFuncAttributeMaxDynamicSharedMemorySize, DYN);

    hipLaunchKernelGGL(k_zero, dim3(24), dim3(256), 0, stream, cnt);
    hipLaunchKernelGGL(k_transpose_x, dim3((Tx * INx * Bx + 255) / 256), dim3(256), 0, stream, x, xT);
    hipLaunchKernelGGL(k_transpose_oh, dim3((Ux * Vx * Bx + 255) / 256), dim3(256), 0, stream, oneh, ohT);

    // Layer 0: single launch, 800 steps
    hipLaunchKernelGGL((k_rec<1>), dim3(128), dim3(640), DYN, stream,
                       Whh0, (const float*)nullptr, xT, h0i, Wih0, bih0, bhh0,
                       out0, cnt + 0, 0, Tx);

    hipLaunchKernelGGL(k_abk, dim3(Tx), dim3(256), 0, stream, out0, Wwin, bwin, abk);
    hipLaunchKernelGGL(k_cumsum, dim3(10), dim3(64), 0, stream, abk);
    hipLaunchKernelGGL(k_window, dim3(Tx), dim3(256), 0, stream, abk, ohT, winb);

    // Layer 1: chunked xg + recurrence (flags continue across chunks, region 1)
    for (int c = 0; c < NC; c++) {
        hipLaunchKernelGGL(k_xg, dim3(TT, 75), dim3(256), 0, stream,
                           out0, winb, xT, Wih1, bih1, xg, c * TT);
        hipLaunchKernelGGL((k_rec<0>), dim3(128), dim3(640), DYN, stream,
                           Whh1, xg, xT, h1i, (const float*)nullptr, bih1, bhh1,
                           out12, cnt + 2048, c * TT, TT);
    }
    // Layer 2 (same weights), fresh flag region 2; output reuses out0
    for (int c = 0; c < NC; c++) {
        hipLaunchKernelGGL(k_xg, dim3(TT, 75), dim3(256), 0, stream,
                           out12, winb, xT, Wih1, bih1, xg, c * TT);
        hipLaunchKernelGGL((k_rec<0>), dim3(128), dim3(640), DYN, stream,
                           Whh1, xg, xT, h2i, (const float*)nullptr, bih1, bhh1,
                           out0, cnt + 4096, c * TT, TT);
    }
    hipLaunchKernelGGL(k_mdn, dim3(Tx), dim3(256), 0, stream, out0, Wmdn, bmdn, (float*)d_out);
}